// Round 1
// baseline (236.451 us; speedup 1.0000x reference)
//
#include <hip/hip_runtime.h>
#include <stdint.h>

#define N 8192
#define C 512
#define BM 128
#define BN 128
#define BK 64
#define NSPLIT 16
#define COLS_PER_SPLIT (N / NSPLIT)   /* 512 */
#define CT (COLS_PER_SPLIT / BN)      /* 4 */
#define INV_T 14.285714285714286f

typedef __attribute__((ext_vector_type(8))) short bf16x8;
typedef __attribute__((ext_vector_type(4))) float f32x4;

__device__ __forceinline__ ushort f2bf(float f) {
  uint32_t u = __float_as_uint(f);
  u += 0x7FFFu + ((u >> 16) & 1u);   // round-to-nearest-even
  return (ushort)(u >> 16);
}

// ---- fp32 -> bf16 conversion, 4 elements/thread ----
__global__ __launch_bounds__(256) void cvt_kernel(const float* __restrict__ src,
                                                  ushort* __restrict__ dst) {
  int i = blockIdx.x * 256 + threadIdx.x;
  float4 v = ((const float4*)src)[i];
  ushort4 o;
  o.x = f2bf(v.x); o.y = f2bf(v.y); o.z = f2bf(v.z); o.w = f2bf(v.w);
  ((ushort4*)dst)[i] = o;
}

// ---- diagonal: pos[i] = (X_i . Y_i) / temp, one wave per row, fp32 ----
__global__ __launch_bounds__(256) void pos_kernel(const float* __restrict__ X,
                                                  const float* __restrict__ Y,
                                                  float* __restrict__ pos) {
  int gid = blockIdx.x * 256 + threadIdx.x;
  int row = gid >> 6;
  int lane = gid & 63;
  const float4* xr = (const float4*)(X + (size_t)row * C);
  const float4* yr = (const float4*)(Y + (size_t)row * C);
  float4 a = xr[lane], b = yr[lane];
  float s = a.x * b.x + a.y * b.y + a.z * b.z + a.w * b.w;
  a = xr[lane + 64]; b = yr[lane + 64];
  s += a.x * b.x + a.y * b.y + a.z * b.z + a.w * b.w;
#pragma unroll
  for (int off = 32; off >= 1; off >>= 1) s += __shfl_xor(s, off);
  if (lane == 0) pos[row] = s * INV_T;
}

// ---- main: fused 128x128-tile bf16 MFMA GEMM + online logsumexp partials ----
__global__ __launch_bounds__(256) void gemm_lse_kernel(const ushort* __restrict__ Xbf,
                                                       const ushort* __restrict__ Ybf,
                                                       float2* __restrict__ partials) {
  __shared__ ushort As[BM][BK];   // 16 KB
  __shared__ ushort Bs[BN][BK];   // 16 KB
  __shared__ float pm[2][BM];
  __shared__ float pl[2][BM];
  __shared__ float m_run[BM];
  __shared__ float l_run[BM];

  const int tid = threadIdx.x;
  const int bx = blockIdx.x;
  const int split = bx & (NSPLIT - 1);
  const int rb = bx >> 4;                 // 0..63
  const int row0 = rb * BM;
  const int colbase = split * COLS_PER_SPLIT;

  const int wave = tid >> 6;
  const int lane = tid & 63;
  const int q = lane >> 4;
  const int mcol = lane & 15;
  const int wr = wave >> 1;   // wave row: rows [wr*64, wr*64+64)
  const int wc = wave & 1;    // wave col: cols [wc*64, wc*64+64)

  if (tid < BM) { m_run[tid] = -INFINITY; l_run[tid] = 0.0f; }

  for (int ct = 0; ct < CT; ++ct) {
    const int col0 = colbase + ct * BN;
    f32x4 acc[4][4];
#pragma unroll
    for (int i = 0; i < 4; ++i)
#pragma unroll
      for (int j = 0; j < 4; ++j) acc[i][j] = f32x4{0.f, 0.f, 0.f, 0.f};

    for (int k0 = 0; k0 < C; k0 += BK) {
      // stage A[128][64] and B[128][64] bf16 tiles via async global->LDS, 16B/lane
#pragma unroll
      for (int i = 0; i < 4; ++i) {
        int s = i * 256 + tid;            // 16B segment id, 0..1023
        int r = s >> 3;
        int kc = (s & 7) << 3;
        const ushort* ga = Xbf + (size_t)(row0 + r) * C + (k0 + kc);
        const ushort* gb = Ybf + (size_t)(col0 + r) * C + (k0 + kc);
        uint32_t loff = (uint32_t)((i * 256 + (tid & ~63)) * 16); // wave-uniform base
        __builtin_amdgcn_global_load_lds(
            (const __attribute__((address_space(1))) uint32_t*)(uintptr_t)ga,
            (__attribute__((address_space(3))) uint32_t*)(uintptr_t)((char*)&As[0][0] + loff),
            16, 0, 0);
        __builtin_amdgcn_global_load_lds(
            (const __attribute__((address_space(1))) uint32_t*)(uintptr_t)gb,
            (__attribute__((address_space(3))) uint32_t*)(uintptr_t)((char*)&Bs[0][0] + loff),
            16, 0, 0);
      }
      __syncthreads();
#pragma unroll
      for (int kb = 0; kb < BK; kb += 32) {
        bf16x8 af[4], bfr[4];
#pragma unroll
        for (int t = 0; t < 4; ++t) {
          af[t]  = *(const bf16x8*)&As[wr * 64 + t * 16 + mcol][kb + q * 8];
          bfr[t] = *(const bf16x8*)&Bs[wc * 64 + t * 16 + mcol][kb + q * 8];
        }
#pragma unroll
        for (int ti = 0; ti < 4; ++ti)
#pragma unroll
          for (int tj = 0; tj < 4; ++tj)
            acc[ti][tj] = __builtin_amdgcn_mfma_f32_16x16x32_bf16(af[ti], bfr[tj], acc[ti][tj], 0, 0, 0);
      }
      __syncthreads();
    }

    // epilogue: per-row max & sum-exp over this 128-col tile, then online merge
#pragma unroll
    for (int ti = 0; ti < 4; ++ti) {
#pragma unroll
      for (int r = 0; r < 4; ++r) {
        float v0 = acc[ti][0][r] * INV_T;
        float v1 = acc[ti][1][r] * INV_T;
        float v2 = acc[ti][2][r] * INV_T;
        float v3 = acc[ti][3][r] * INV_T;
        float mx = fmaxf(fmaxf(v0, v1), fmaxf(v2, v3));
#pragma unroll
        for (int off = 1; off < 16; off <<= 1) mx = fmaxf(mx, __shfl_xor(mx, off));
        float se = __expf(v0 - mx) + __expf(v1 - mx) + __expf(v2 - mx) + __expf(v3 - mx);
#pragma unroll
        for (int off = 1; off < 16; off <<= 1) se += __shfl_xor(se, off);
        if (mcol == 0) {
          int row = wr * 64 + ti * 16 + q * 4 + r;
          pm[wc][row] = mx;
          pl[wc][row] = se;
        }
      }
    }
    __syncthreads();
    if (tid < BM) {
      float m0 = pm[0][tid], l0 = pl[0][tid];
      float m1 = pm[1][tid], l1 = pl[1][tid];
      float mo = m_run[tid], lo = l_run[tid];
      float mn = fmaxf(fmaxf(m0, m1), mo);
      float ln = l0 * __expf(m0 - mn) + l1 * __expf(m1 - mn) + lo * __expf(mo - mn);
      m_run[tid] = mn; l_run[tid] = ln;
    }
    __syncthreads();
  }

  if (tid < BM) {
    partials[(size_t)(row0 + tid) * NSPLIT + split] = make_float2(m_run[tid], l_run[tid]);
  }
}

// ---- combine: per-row merge of NSPLIT partials, subtract pos, global sum ----
__global__ __launch_bounds__(256) void combine_kernel(const float2* __restrict__ partials,
                                                      const float* __restrict__ pos,
                                                      float* __restrict__ out) {
  int row = blockIdx.x * 256 + threadIdx.x;
  const float2* pr = partials + (size_t)row * NSPLIT;
  float M = -INFINITY;
  float2 p[NSPLIT];
#pragma unroll
  for (int s = 0; s < NSPLIT; ++s) { p[s] = pr[s]; M = fmaxf(M, p[s].x); }
  float L = 0.0f;
#pragma unroll
  for (int s = 0; s < NSPLIT; ++s) L += p[s].y * __expf(p[s].x - M);
  float v = M + __logf(L) - pos[row];
#pragma unroll
  for (int off = 32; off >= 1; off >>= 1) v += __shfl_xor(v, off);
  __shared__ float wsum[4];
  if ((threadIdx.x & 63) == 0) wsum[threadIdx.x >> 6] = v;
  __syncthreads();
  if (threadIdx.x == 0) atomicAdd(out, wsum[0] + wsum[1] + wsum[2] + wsum[3]);
}

extern "C" void kernel_launch(void* const* d_in, const int* in_sizes, int n_in,
                              void* d_out, int out_size, void* d_ws, size_t ws_size,
                              hipStream_t stream) {
  const float* X = (const float*)d_in[0];
  const float* Y = (const float*)d_in[1];
  float* out = (float*)d_out;

  // workspace layout: Xbf (8 MB) | Ybf (8 MB) | partials (1 MB) | pos (32 KB)
  char* w = (char*)d_ws;
  ushort* Xbf = (ushort*)w;
  ushort* Ybf = Xbf + (size_t)N * C;
  float2* partials = (float2*)(Ybf + (size_t)N * C);
  float* pos = (float*)((char*)partials + (size_t)N * NSPLIT * sizeof(float2));

  hipMemsetAsync(d_out, 0, sizeof(float), stream);
  cvt_kernel<<<(N * C / 4) / 256, 256, 0, stream>>>(X, Xbf);
  cvt_kernel<<<(N * C / 4) / 256, 256, 0, stream>>>(Y, Ybf);
  pos_kernel<<<(N * 64) / 256, 256, 0, stream>>>(X, Y, pos);
  gemm_lse_kernel<<<64 * NSPLIT, 256, 0, stream>>>(Xbf, Ybf, partials);
  combine_kernel<<<N / 256, 256, 0, stream>>>(partials, pos, out);
}

// Round 2
// 179.213 us; speedup vs baseline: 1.3194x; 1.3194x over previous
//
#include <hip/hip_runtime.h>
#include <stdint.h>

#define N 8192
#define C 512
#define BM 128
#define BN 128
#define BK 64
#define NSPLIT 16
#define COLS_PER_SPLIT (N / NSPLIT)   /* 512 */
#define CT (COLS_PER_SPLIT / BN)      /* 4 */
#define INV_T 14.285714285714286f

typedef __attribute__((ext_vector_type(8))) short bf16x8;
typedef __attribute__((ext_vector_type(8))) unsigned short u16x8;
typedef __attribute__((ext_vector_type(4))) float f32x4;

__device__ __forceinline__ ushort f2bf(float f) {
  uint32_t u = __float_as_uint(f);
  u += 0x7FFFu + ((u >> 16) & 1u);   // round-to-nearest-even
  return (ushort)(u >> 16);
}

// ---- fused prep: fp32->bf16 for X and Y + diagonal pos, one wave per row ----
__global__ __launch_bounds__(256) void prep_kernel(const float* __restrict__ X,
                                                   const float* __restrict__ Y,
                                                   ushort* __restrict__ Xbf,
                                                   ushort* __restrict__ Ybf,
                                                   float* __restrict__ pos) {
  const int wave = threadIdx.x >> 6;
  const int lane = threadIdx.x & 63;
  const int row = blockIdx.x * 4 + wave;
  const float4* xr = (const float4*)(X + (size_t)row * C) + lane * 2;
  const float4* yr = (const float4*)(Y + (size_t)row * C) + lane * 2;
  float4 x0 = xr[0], x1 = xr[1];
  float4 y0 = yr[0], y1 = yr[1];
  float s = x0.x * y0.x + x0.y * y0.y + x0.z * y0.z + x0.w * y0.w
          + x1.x * y1.x + x1.y * y1.y + x1.z * y1.z + x1.w * y1.w;
  u16x8 ox = { f2bf(x0.x), f2bf(x0.y), f2bf(x0.z), f2bf(x0.w),
               f2bf(x1.x), f2bf(x1.y), f2bf(x1.z), f2bf(x1.w) };
  u16x8 oy = { f2bf(y0.x), f2bf(y0.y), f2bf(y0.z), f2bf(y0.w),
               f2bf(y1.x), f2bf(y1.y), f2bf(y1.z), f2bf(y1.w) };
  ((u16x8*)(Xbf + (size_t)row * C))[lane] = ox;
  ((u16x8*)(Ybf + (size_t)row * C))[lane] = oy;
#pragma unroll
  for (int off = 32; off >= 1; off >>= 1) s += __shfl_xor(s, off);
  if (lane == 0) pos[row] = s * INV_T;
}

// ---- main: fused 128x128-tile bf16 MFMA GEMM + online logsumexp partials ----
// LDS layout is XOR-swizzled: logical 16B chunk j of row r lives at physical
// chunk j ^ (r&7). Staging stays contiguous (global_load_lds requirement);
// fragment reads spread uniformly over all 8 bank groups (2 lanes/group = free).
__global__ __launch_bounds__(256) void gemm_lse_kernel(const ushort* __restrict__ Xbf,
                                                       const ushort* __restrict__ Ybf,
                                                       float2* __restrict__ partials) {
  __shared__ ushort As[BM][BK];   // 16 KB (physical, swizzled)
  __shared__ ushort Bs[BN][BK];   // 16 KB
  __shared__ float pm[2][BM];
  __shared__ float pl[2][BM];

  const int tid = threadIdx.x;
  const int bx = blockIdx.x;
  const int split = bx & (NSPLIT - 1);
  const int rb = bx >> 4;                 // 0..63
  const int row0 = rb * BM;
  const int colbase = split * COLS_PER_SPLIT;

  const int wave = tid >> 6;
  const int lane = tid & 63;
  const int q = lane >> 4;
  const int mcol = lane & 15;
  const int swz = mcol & 7;   // fragment-read swizzle (row&7 == mcol&7)
  const int wr = wave >> 1;   // wave row: rows [wr*64, wr*64+64)
  const int wc = wave & 1;    // wave col: cols [wc*64, wc*64+64)

  // per-lane online softmax state: 16 rows/lane (ti*4+r), duplicated across mcol
  float m_s[16], l_s[16];
#pragma unroll
  for (int s = 0; s < 16; ++s) { m_s[s] = -INFINITY; l_s[s] = 0.0f; }

  for (int ct = 0; ct < CT; ++ct) {
    const int col0 = colbase + ct * BN;
    f32x4 acc[4][4];
#pragma unroll
    for (int i = 0; i < 4; ++i)
#pragma unroll
      for (int j = 0; j < 4; ++j) acc[i][j] = f32x4{0.f, 0.f, 0.f, 0.f};

    for (int k0 = 0; k0 < C; k0 += BK) {
      // stage A[128][64] and B[128][64] bf16 tiles, 16B/lane, XOR-swizzled source
#pragma unroll
      for (int i = 0; i < 4; ++i) {
        int s = i * 256 + tid;            // physical 16B chunk id, 0..1023
        int r = s >> 3;                   // row
        int p = s & 7;                    // physical chunk within row
        int j = p ^ (r & 7);              // logical chunk to fetch
        const ushort* ga = Xbf + (size_t)(row0 + r) * C + (k0 + j * 8);
        const ushort* gb = Ybf + (size_t)(col0 + r) * C + (k0 + j * 8);
        uint32_t loff = (uint32_t)((i * 256 + (tid & ~63)) * 16); // wave-uniform base
        __builtin_amdgcn_global_load_lds(
            (const __attribute__((address_space(1))) uint32_t*)(uintptr_t)ga,
            (__attribute__((address_space(3))) uint32_t*)(uintptr_t)((char*)&As[0][0] + loff),
            16, 0, 0);
        __builtin_amdgcn_global_load_lds(
            (const __attribute__((address_space(1))) uint32_t*)(uintptr_t)gb,
            (__attribute__((address_space(3))) uint32_t*)(uintptr_t)((char*)&Bs[0][0] + loff),
            16, 0, 0);
      }
      __syncthreads();
#pragma unroll
      for (int kb = 0; kb < BK; kb += 32) {
        const int ca = ((kb >> 3) + q) ^ swz;   // physical chunk column
        bf16x8 af[4], bfr[4];
#pragma unroll
        for (int t = 0; t < 4; ++t) {
          af[t]  = *(const bf16x8*)&As[wr * 64 + t * 16 + mcol][ca * 8];
          bfr[t] = *(const bf16x8*)&Bs[wc * 64 + t * 16 + mcol][ca * 8];
        }
#pragma unroll
        for (int ti = 0; ti < 4; ++ti)
#pragma unroll
          for (int tj = 0; tj < 4; ++tj)
            acc[ti][tj] = __builtin_amdgcn_mfma_f32_16x16x32_bf16(af[ti], bfr[tj], acc[ti][tj], 0, 0, 0);
      }
      __syncthreads();
    }

    // per-lane online update over this 128-col tile: no shuffles, no barriers
#pragma unroll
    for (int ti = 0; ti < 4; ++ti) {
#pragma unroll
      for (int r = 0; r < 4; ++r) {
        const int s = ti * 4 + r;
        float v0 = acc[ti][0][r] * INV_T;
        float v1 = acc[ti][1][r] * INV_T;
        float v2 = acc[ti][2][r] * INV_T;
        float v3 = acc[ti][3][r] * INV_T;
        float mx = fmaxf(fmaxf(v0, v1), fmaxf(v2, v3));
        float mn = fmaxf(m_s[s], mx);
        l_s[s] = l_s[s] * __expf(m_s[s] - mn)
               + __expf(v0 - mn) + __expf(v1 - mn) + __expf(v2 - mn) + __expf(v3 - mn);
        m_s[s] = mn;
      }
    }
  }

  // final cross-lane merge (across the 16 mcol lanes that share rows)
#pragma unroll
  for (int s = 0; s < 16; ++s) {
    float m = m_s[s], l = l_s[s];
#pragma unroll
    for (int off = 1; off < 16; off <<= 1) {
      float mo = __shfl_xor(m, off);
      float lo = __shfl_xor(l, off);
      float mn = fmaxf(m, mo);
      l = l * __expf(m - mn) + lo * __expf(mo - mn);
      m = mn;
    }
    m_s[s] = m; l_s[s] = l;
  }
  if (mcol == 0) {
#pragma unroll
    for (int ti = 0; ti < 4; ++ti)
#pragma unroll
      for (int r = 0; r < 4; ++r) {
        int row = wr * 64 + ti * 16 + q * 4 + r;
        pm[wc][row] = m_s[ti * 4 + r];
        pl[wc][row] = l_s[ti * 4 + r];
      }
  }
  __syncthreads();
  if (tid < BM) {
    float m0 = pm[0][tid], l0 = pl[0][tid];
    float m1 = pm[1][tid], l1 = pl[1][tid];
    float mn = fmaxf(m0, m1);
    float ln = l0 * __expf(m0 - mn) + l1 * __expf(m1 - mn);
    partials[(size_t)(row0 + tid) * NSPLIT + split] = make_float2(mn, ln);
  }
}

// ---- combine: per-row merge of NSPLIT partials, subtract pos, global sum ----
__global__ __launch_bounds__(256) void combine_kernel(const float2* __restrict__ partials,
                                                      const float* __restrict__ pos,
                                                      float* __restrict__ out) {
  int row = blockIdx.x * 256 + threadIdx.x;
  const float2* pr = partials + (size_t)row * NSPLIT;
  float M = -INFINITY;
  float2 p[NSPLIT];
#pragma unroll
  for (int s = 0; s < NSPLIT; ++s) { p[s] = pr[s]; M = fmaxf(M, p[s].x); }
  float L = 0.0f;
#pragma unroll
  for (int s = 0; s < NSPLIT; ++s) L += p[s].y * __expf(p[s].x - M);
  float v = M + __logf(L) - pos[row];
#pragma unroll
  for (int off = 32; off >= 1; off >>= 1) v += __shfl_xor(v, off);
  __shared__ float wsum[4];
  if ((threadIdx.x & 63) == 0) wsum[threadIdx.x >> 6] = v;
  __syncthreads();
  if (threadIdx.x == 0) atomicAdd(out, wsum[0] + wsum[1] + wsum[2] + wsum[3]);
}

extern "C" void kernel_launch(void* const* d_in, const int* in_sizes, int n_in,
                              void* d_out, int out_size, void* d_ws, size_t ws_size,
                              hipStream_t stream) {
  const float* X = (const float*)d_in[0];
  const float* Y = (const float*)d_in[1];
  float* out = (float*)d_out;

  // workspace layout: Xbf (8 MB) | Ybf (8 MB) | partials (1 MB) | pos (32 KB)
  char* w = (char*)d_ws;
  ushort* Xbf = (ushort*)w;
  ushort* Ybf = Xbf + (size_t)N * C;
  float2* partials = (float2*)(Ybf + (size_t)N * C);
  float* pos = (float*)((char*)partials + (size_t)N * NSPLIT * sizeof(float2));

  hipMemsetAsync(d_out, 0, sizeof(float), stream);
  prep_kernel<<<N / 4, 256, 0, stream>>>(X, Y, Xbf, Ybf, pos);
  gemm_lse_kernel<<<64 * NSPLIT, 256, 0, stream>>>(Xbf, Ybf, partials);
  combine_kernel<<<N / 256, 256, 0, stream>>>(partials, pos, out);
}

// Round 3
// 167.639 us; speedup vs baseline: 1.4105x; 1.0690x over previous
//
#include <hip/hip_runtime.h>
#include <hip/hip_fp8.h>
#include <stdint.h>

#define N 8192
#define C 512
#define BM 128
#define BN 128
#define BKF 128                       /* fp8 elements (bytes) per K-tile */
#define NSPLIT 16
#define COLS_PER_SPLIT (N / NSPLIT)   /* 512 */
#define CT (COLS_PER_SPLIT / BN)      /* 4 */
#define INV_T 14.285714285714286f

typedef __attribute__((ext_vector_type(4))) float f32x4;

__device__ __forceinline__ unsigned char f2e4m3(float f) {
  __hip_fp8_e4m3 t(f);
  return (unsigned char)t.__x;
}

// ---- fused prep: fp32 -> fp8 e4m3 for X and Y + exact fp32 diagonal pos ----
// one wave per row (C=512 floats, 8/lane)
__global__ __launch_bounds__(256) void prep_kernel(const float* __restrict__ X,
                                                   const float* __restrict__ Y,
                                                   unsigned char* __restrict__ Xf8,
                                                   unsigned char* __restrict__ Yf8,
                                                   float* __restrict__ pos) {
  const int wave = threadIdx.x >> 6;
  const int lane = threadIdx.x & 63;
  const int row = blockIdx.x * 4 + wave;
  const float4* xr = (const float4*)(X + (size_t)row * C) + lane * 2;
  const float4* yr = (const float4*)(Y + (size_t)row * C) + lane * 2;
  float4 x0 = xr[0], x1 = xr[1];
  float4 y0 = yr[0], y1 = yr[1];
  float s = x0.x * y0.x + x0.y * y0.y + x0.z * y0.z + x0.w * y0.w
          + x1.x * y1.x + x1.y * y1.y + x1.z * y1.z + x1.w * y1.w;
  union { unsigned char b[8]; unsigned long long u; } ox, oy;
  ox.b[0] = f2e4m3(x0.x); ox.b[1] = f2e4m3(x0.y); ox.b[2] = f2e4m3(x0.z); ox.b[3] = f2e4m3(x0.w);
  ox.b[4] = f2e4m3(x1.x); ox.b[5] = f2e4m3(x1.y); ox.b[6] = f2e4m3(x1.z); ox.b[7] = f2e4m3(x1.w);
  oy.b[0] = f2e4m3(y0.x); oy.b[1] = f2e4m3(y0.y); oy.b[2] = f2e4m3(y0.z); oy.b[3] = f2e4m3(y0.w);
  oy.b[4] = f2e4m3(y1.x); oy.b[5] = f2e4m3(y1.y); oy.b[6] = f2e4m3(y1.z); oy.b[7] = f2e4m3(y1.w);
  ((unsigned long long*)(Xf8 + (size_t)row * C))[lane] = ox.u;
  ((unsigned long long*)(Yf8 + (size_t)row * C))[lane] = oy.u;
#pragma unroll
  for (int off = 32; off >= 1; off >>= 1) s += __shfl_xor(s, off);
  if (lane == 0) pos[row] = s * INV_T;
}

// ---- main: fused 128x128-tile fp8 MFMA GEMM + online logsumexp partials ----
// LDS XOR-swizzle: logical 16B chunk j of row r lives at physical chunk j^(r&7).
// Staging stays contiguous (global_load_lds wave-uniform-base requirement);
// b64 fragment reads land 2 lanes per 8B slot per 32-lane phase = conflict-free.
__global__ __launch_bounds__(256, 3) void gemm_lse_kernel(const unsigned char* __restrict__ Xf8,
                                                          const unsigned char* __restrict__ Yf8,
                                                          float2* __restrict__ partials) {
  __shared__ unsigned char As[BM][BKF];   // 16 KB (physical, swizzled)
  __shared__ unsigned char Bs[BN][BKF];   // 16 KB
  __shared__ float pm[2][BM];
  __shared__ float pl[2][BM];

  const int tid = threadIdx.x;
  const int bx = blockIdx.x;
  const int split = bx & (NSPLIT - 1);
  const int rb = bx >> 4;                 // 0..63
  const int row0 = rb * BM;
  const int colbase = split * COLS_PER_SPLIT;

  const int wave = tid >> 6;
  const int lane = tid & 63;
  const int q = lane >> 4;
  const int mcol = lane & 15;
  const int swz = mcol & 7;               // row&7 == mcol&7 for fragment rows
  const int wr = wave >> 1;               // wave row: rows [wr*64, +64)
  const int wc = wave & 1;                // wave col: cols [wc*64, +64)
  const int subq = (q & 1) * 8;           // byte half within 16B chunk
  const int qh = q >> 1;

  // per-lane online softmax state: 16 rows/lane, duplicated across mcol lanes
  float m_s[16], l_s[16];
#pragma unroll
  for (int s = 0; s < 16; ++s) { m_s[s] = -INFINITY; l_s[s] = 0.0f; }

  // staging-lane invariants
  const int r_base = tid >> 3;            // row within 32-row group
  const int p = tid & 7;                  // physical chunk within row
  const int j = p ^ (r_base & 7);         // logical chunk (invariant across i: 32i ≡ 0 mod 8)

  for (int ct = 0; ct < CT; ++ct) {
    const int col0 = colbase + ct * BN;
    f32x4 acc[4][4];
#pragma unroll
    for (int i = 0; i < 4; ++i)
#pragma unroll
      for (int jj = 0; jj < 4; ++jj) acc[i][jj] = f32x4{0.f, 0.f, 0.f, 0.f};

    for (int k0 = 0; k0 < C; k0 += BKF) {
      // stage A[128][128B] and B[128][128B], 16B/lane, XOR-swizzled source
#pragma unroll
      for (int i = 0; i < 4; ++i) {
        const int r = i * 32 + r_base;
        const unsigned char* ga = Xf8 + (size_t)(row0 + r) * C + (k0 + j * 16);
        const unsigned char* gb = Yf8 + (size_t)(col0 + r) * C + (k0 + j * 16);
        uint32_t loff = (uint32_t)((i * 256 + (tid & ~63)) * 16); // wave-uniform base
        __builtin_amdgcn_global_load_lds(
            (const __attribute__((address_space(1))) uint32_t*)(uintptr_t)ga,
            (__attribute__((address_space(3))) uint32_t*)(uintptr_t)((char*)&As[0][0] + loff),
            16, 0, 0);
        __builtin_amdgcn_global_load_lds(
            (const __attribute__((address_space(1))) uint32_t*)(uintptr_t)gb,
            (__attribute__((address_space(3))) uint32_t*)(uintptr_t)((char*)&Bs[0][0] + loff),
            16, 0, 0);
      }
      __syncthreads();
#pragma unroll
      for (int s = 0; s < 4; ++s) {
        const int inrow = (((2 * s + qh) ^ swz) * 16) + subq;  // physical byte offset
        long long af[4], bfr[4];
#pragma unroll
        for (int t = 0; t < 4; ++t) {
          af[t]  = *(const long long*)&As[wr * 64 + t * 16 + mcol][inrow];
          bfr[t] = *(const long long*)&Bs[wc * 64 + t * 16 + mcol][inrow];
        }
#pragma unroll
        for (int ti = 0; ti < 4; ++ti)
#pragma unroll
          for (int tj = 0; tj < 4; ++tj)
            acc[ti][tj] = __builtin_amdgcn_mfma_f32_16x16x32_fp8_fp8(af[ti], bfr[tj], acc[ti][tj], 0, 0, 0);
      }
      __syncthreads();
    }

    // per-lane online update over this 128-col tile: no shuffles, no barriers
#pragma unroll
    for (int ti = 0; ti < 4; ++ti) {
#pragma unroll
      for (int r = 0; r < 4; ++r) {
        const int s = ti * 4 + r;
        float v0 = acc[ti][0][r] * INV_T;
        float v1 = acc[ti][1][r] * INV_T;
        float v2 = acc[ti][2][r] * INV_T;
        float v3 = acc[ti][3][r] * INV_T;
        float mx = fmaxf(fmaxf(v0, v1), fmaxf(v2, v3));
        float mn = fmaxf(m_s[s], mx);
        l_s[s] = l_s[s] * __expf(m_s[s] - mn)
               + __expf(v0 - mn) + __expf(v1 - mn) + __expf(v2 - mn) + __expf(v3 - mn);
        m_s[s] = mn;
      }
    }
  }

  // final cross-lane merge (across the 16 mcol lanes that share rows)
#pragma unroll
  for (int s = 0; s < 16; ++s) {
    float m = m_s[s], l = l_s[s];
#pragma unroll
    for (int off = 1; off < 16; off <<= 1) {
      float mo = __shfl_xor(m, off);
      float lo = __shfl_xor(l, off);
      float mn = fmaxf(m, mo);
      l = l * __expf(m - mn) + lo * __expf(mo - mn);
      m = mn;
    }
    m_s[s] = m; l_s[s] = l;
  }
  if (mcol == 0) {
#pragma unroll
    for (int ti = 0; ti < 4; ++ti)
#pragma unroll
      for (int r = 0; r < 4; ++r) {
        int row = wr * 64 + ti * 16 + q * 4 + r;
        pm[wc][row] = m_s[ti * 4 + r];
        pl[wc][row] = l_s[ti * 4 + r];
      }
  }
  __syncthreads();
  if (tid < BM) {
    float m0 = pm[0][tid], l0 = pl[0][tid];
    float m1 = pm[1][tid], l1 = pl[1][tid];
    float mn = fmaxf(m0, m1);
    float ln = l0 * __expf(m0 - mn) + l1 * __expf(m1 - mn);
    partials[(size_t)(row0 + tid) * NSPLIT + split] = make_float2(mn, ln);
  }
}

// ---- combine: per-row merge of NSPLIT partials, subtract pos, global sum ----
__global__ __launch_bounds__(256) void combine_kernel(const float2* __restrict__ partials,
                                                      const float* __restrict__ pos,
                                                      float* __restrict__ out) {
  int row = blockIdx.x * 256 + threadIdx.x;
  const float2* pr = partials + (size_t)row * NSPLIT;
  float M = -INFINITY;
  float2 p[NSPLIT];
#pragma unroll
  for (int s = 0; s < NSPLIT; ++s) { p[s] = pr[s]; M = fmaxf(M, p[s].x); }
  float L = 0.0f;
#pragma unroll
  for (int s = 0; s < NSPLIT; ++s) L += p[s].y * __expf(p[s].x - M);
  float v = M + __logf(L) - pos[row];
#pragma unroll
  for (int off = 32; off >= 1; off >>= 1) v += __shfl_xor(v, off);
  __shared__ float wsum[4];
  if ((threadIdx.x & 63) == 0) wsum[threadIdx.x >> 6] = v;
  __syncthreads();
  if (threadIdx.x == 0) atomicAdd(out, wsum[0] + wsum[1] + wsum[2] + wsum[3]);
}

extern "C" void kernel_launch(void* const* d_in, const int* in_sizes, int n_in,
                              void* d_out, int out_size, void* d_ws, size_t ws_size,
                              hipStream_t stream) {
  const float* X = (const float*)d_in[0];
  const float* Y = (const float*)d_in[1];
  float* out = (float*)d_out;

  // workspace: Xf8 (4MB) | Yf8 (4MB) | partials (1MB) | pos (32KB)
  char* w = (char*)d_ws;
  unsigned char* Xf8 = (unsigned char*)w;
  unsigned char* Yf8 = Xf8 + (size_t)N * C;
  float2* partials = (float2*)(Yf8 + (size_t)N * C);
  float* pos = (float*)((char*)partials + (size_t)N * NSPLIT * sizeof(float2));

  hipMemsetAsync(d_out, 0, sizeof(float), stream);
  prep_kernel<<<N / 4, 256, 0, stream>>>(X, Y, Xf8, Yf8, pos);
  gemm_lse_kernel<<<64 * NSPLIT, 256, 0, stream>>>(Xf8, Yf8, partials);
  combine_kernel<<<N / 256, 256, 0, stream>>>(partials, pos, out);
}

// Round 4
// 140.169 us; speedup vs baseline: 1.6869x; 1.1960x over previous
//
#include <hip/hip_runtime.h>
#include <stdint.h>

#define N 8192
#define C 512
#define BM 128
#define BN 128
#define BKF 128                       /* fp8 bytes per K-tile */
#define NSPLIT 16
#define COLS_PER_SPLIT (N / NSPLIT)   /* 512 */
#define CT (COLS_PER_SPLIT / BN)      /* 4 */
#define INV_T 14.285714285714286f

typedef __attribute__((ext_vector_type(4)))  int   i32x4;
typedef __attribute__((ext_vector_type(8)))  int   i32x8;
typedef __attribute__((ext_vector_type(16))) float f32x16;

// ---- fused prep: fp32 -> fp8 e4m3 (HW cvt) for X and Y + exact fp32 pos ----
// one wave per row (C=512 floats, 8/lane)
__global__ __launch_bounds__(256) void prep_kernel(const float* __restrict__ X,
                                                   const float* __restrict__ Y,
                                                   unsigned char* __restrict__ Xf8,
                                                   unsigned char* __restrict__ Yf8,
                                                   float* __restrict__ pos) {
  const int wave = threadIdx.x >> 6;
  const int lane = threadIdx.x & 63;
  const int row = blockIdx.x * 4 + wave;
  const float4* xr = (const float4*)(X + (size_t)row * C) + lane * 2;
  const float4* yr = (const float4*)(Y + (size_t)row * C) + lane * 2;
  float4 x0 = xr[0], x1 = xr[1];
  float4 y0 = yr[0], y1 = yr[1];
  float s = x0.x * y0.x + x0.y * y0.y + x0.z * y0.z + x0.w * y0.w
          + x1.x * y1.x + x1.y * y1.y + x1.z * y1.z + x1.w * y1.w;
  int2 ox, oy;
  ox.x = __builtin_amdgcn_cvt_pk_fp8_f32(x0.x, x0.y, 0, false);
  ox.x = __builtin_amdgcn_cvt_pk_fp8_f32(x0.z, x0.w, ox.x, true);
  ox.y = __builtin_amdgcn_cvt_pk_fp8_f32(x1.x, x1.y, 0, false);
  ox.y = __builtin_amdgcn_cvt_pk_fp8_f32(x1.z, x1.w, ox.y, true);
  oy.x = __builtin_amdgcn_cvt_pk_fp8_f32(y0.x, y0.y, 0, false);
  oy.x = __builtin_amdgcn_cvt_pk_fp8_f32(y0.z, y0.w, oy.x, true);
  oy.y = __builtin_amdgcn_cvt_pk_fp8_f32(y1.x, y1.y, 0, false);
  oy.y = __builtin_amdgcn_cvt_pk_fp8_f32(y1.z, y1.w, oy.y, true);
  ((int2*)(Xf8 + (size_t)row * C))[lane] = ox;
  ((int2*)(Yf8 + (size_t)row * C))[lane] = oy;
#pragma unroll
  for (int off = 32; off >= 1; off >>= 1) s += __shfl_xor(s, off);
  if (lane == 0) pos[row] = s * INV_T;
}

// ---- main: 128x128-tile MX-scaled fp8 MFMA (scale=1.0) + online lse ----
// Wave w owns rows [w*32, w*32+32) x all 128 cols: 4x 32x32x64 f8f6f4 accs.
// LDS XOR-swizzle: logical 16B chunk j of row r at physical chunk j^(r&7);
// staging contiguous (global_load_lds); fragment b128 reads: any 8 consecutive
// lanes hit 8 distinct chunks -> conflict-free.
__global__ __launch_bounds__(256, 3) void gemm_lse_kernel(const unsigned char* __restrict__ Xf8,
                                                          const unsigned char* __restrict__ Yf8,
                                                          float2* __restrict__ partials) {
  __shared__ unsigned char As[BM][BKF];   // 16 KB (physical, swizzled)
  __shared__ unsigned char Bs[BN][BKF];   // 16 KB

  const int tid = threadIdx.x;
  const int bx = blockIdx.x;
  const int split = bx & (NSPLIT - 1);
  const int rb = bx >> 4;                 // 0..63
  const int row0 = rb * BM;
  const int colbase = split * COLS_PER_SPLIT;

  const int w = tid >> 6;                 // wave 0..3: rows [w*32, +32)
  const int lane = tid & 63;
  const int lrow = lane & 31;
  const int h = lane >> 5;                // k-half selector
  const int arow = w * 32 + lrow;         // A row for this lane's fragments
  const int swz = lrow & 7;               // == (any fragment row) & 7

  // per-lane online softmax state: 16 rows/lane (reg r -> row (r&3)+8*(r>>2)+4h)
  float m_s[16], l_s[16];
#pragma unroll
  for (int s = 0; s < 16; ++s) { m_s[s] = -INFINITY; l_s[s] = 0.0f; }

  // staging-lane invariants (identical to R3 layout)
  const int r_base = tid >> 3;            // row within 32-row group
  const int p = tid & 7;                  // physical chunk within row
  const int j = p ^ (r_base & 7);         // logical chunk to fetch

  for (int ct = 0; ct < CT; ++ct) {
    const int col0 = colbase + ct * BN;
    f32x16 acc[4];
#pragma unroll
    for (int t = 0; t < 4; ++t)
#pragma unroll
      for (int e = 0; e < 16; ++e) acc[t][e] = 0.0f;

    for (int k0 = 0; k0 < C; k0 += BKF) {
      // stage A[128][128B] and B[128][128B], 16B/lane, XOR-swizzled source
#pragma unroll
      for (int i = 0; i < 4; ++i) {
        const int r = i * 32 + r_base;
        const unsigned char* ga = Xf8 + (size_t)(row0 + r) * C + (k0 + j * 16);
        const unsigned char* gb = Yf8 + (size_t)(col0 + r) * C + (k0 + j * 16);
        uint32_t loff = (uint32_t)((i * 256 + (tid & ~63)) * 16); // wave-uniform base
        __builtin_amdgcn_global_load_lds(
            (const __attribute__((address_space(1))) uint32_t*)(uintptr_t)ga,
            (__attribute__((address_space(3))) uint32_t*)(uintptr_t)((char*)&As[0][0] + loff),
            16, 0, 0);
        __builtin_amdgcn_global_load_lds(
            (const __attribute__((address_space(1))) uint32_t*)(uintptr_t)gb,
            (__attribute__((address_space(3))) uint32_t*)(uintptr_t)((char*)&Bs[0][0] + loff),
            16, 0, 0);
      }
      __syncthreads();
#pragma unroll
      for (int s = 0; s < 2; ++s) {       // two K=64 steps per 128B tile
        const int c0 = 4 * s + 2 * h;     // lane's logical 16B chunk pair
        i32x4 alo = *(const i32x4*)&As[arow][((c0    ) ^ swz) * 16];
        i32x4 ahi = *(const i32x4*)&As[arow][((c0 + 1) ^ swz) * 16];
        i32x8 af = { alo[0], alo[1], alo[2], alo[3], ahi[0], ahi[1], ahi[2], ahi[3] };
#pragma unroll
        for (int tj = 0; tj < 4; ++tj) {
          const int brow = tj * 32 + lrow;
          i32x4 blo = *(const i32x4*)&Bs[brow][((c0    ) ^ swz) * 16];
          i32x4 bhi = *(const i32x4*)&Bs[brow][((c0 + 1) ^ swz) * 16];
          i32x8 bf = { blo[0], blo[1], blo[2], blo[3], bhi[0], bhi[1], bhi[2], bhi[3] };
          // fmt 0/0 = e4m3/e4m3; scale bytes 127 = 2^0 = exact 1.0
          acc[tj] = __builtin_amdgcn_mfma_scale_f32_32x32x64_f8f6f4(
              af, bf, acc[tj], 0, 0, 0, 127, 0, 127);
        }
      }
      __syncthreads();
    }

    // per-lane online update over this 128-col tile (4 cols per row per lane)
#pragma unroll
    for (int r = 0; r < 16; ++r) {
      float v0 = acc[0][r] * INV_T;
      float v1 = acc[1][r] * INV_T;
      float v2 = acc[2][r] * INV_T;
      float v3 = acc[3][r] * INV_T;
      float mx = fmaxf(fmaxf(v0, v1), fmaxf(v2, v3));
      float mn = fmaxf(m_s[r], mx);
      l_s[r] = l_s[r] * __expf(m_s[r] - mn)
             + __expf(v0 - mn) + __expf(v1 - mn) + __expf(v2 - mn) + __expf(v3 - mn);
      m_s[r] = mn;
    }
  }

  // merge across the 32 lanes (cols) sharing each row-set; halves are disjoint rows
#pragma unroll
  for (int r = 0; r < 16; ++r) {
    float m = m_s[r], l = l_s[r];
#pragma unroll
    for (int off = 1; off < 32; off <<= 1) {
      float mo = __shfl_xor(m, off);
      float lo = __shfl_xor(l, off);
      float mn = fmaxf(m, mo);
      l = l * __expf(m - mn) + lo * __expf(mo - mn);
      m = mn;
    }
    m_s[r] = m; l_s[r] = l;
  }
  if (lrow == 0) {
#pragma unroll
    for (int r = 0; r < 16; ++r) {
      int row_local = (r & 3) + 8 * (r >> 2) + 4 * h;
      partials[(size_t)(row0 + w * 32 + row_local) * NSPLIT + split] =
          make_float2(m_s[r], l_s[r]);
    }
  }
}

// ---- combine: per-row merge of NSPLIT partials, subtract pos, global sum ----
__global__ __launch_bounds__(256) void combine_kernel(const float2* __restrict__ partials,
                                                      const float* __restrict__ pos,
                                                      float* __restrict__ out) {
  int row = blockIdx.x * 256 + threadIdx.x;
  const float2* pr = partials + (size_t)row * NSPLIT;
  float M = -INFINITY;
  float2 p[NSPLIT];
#pragma unroll
  for (int s = 0; s < NSPLIT; ++s) { p[s] = pr[s]; M = fmaxf(M, p[s].x); }
  float L = 0.0f;
#pragma unroll
  for (int s = 0; s < NSPLIT; ++s) L += p[s].y * __expf(p[s].x - M);
  float v = M + __logf(L) - pos[row];
#pragma unroll
  for (int off = 32; off >= 1; off >>= 1) v += __shfl_xor(v, off);
  __shared__ float wsum[4];
  if ((threadIdx.x & 63) == 0) wsum[threadIdx.x >> 6] = v;
  __syncthreads();
  if (threadIdx.x == 0) atomicAdd(out, wsum[0] + wsum[1] + wsum[2] + wsum[3]);
}

extern "C" void kernel_launch(void* const* d_in, const int* in_sizes, int n_in,
                              void* d_out, int out_size, void* d_ws, size_t ws_size,
                              hipStream_t stream) {
  const float* X = (const float*)d_in[0];
  const float* Y = (const float*)d_in[1];
  float* out = (float*)d_out;

  // workspace: Xf8 (4MB) | Yf8 (4MB) | partials (1MB) | pos (32KB)
  char* w = (char*)d_ws;
  unsigned char* Xf8 = (unsigned char*)w;
  unsigned char* Yf8 = Xf8 + (size_t)N * C;
  float2* partials = (float2*)(Yf8 + (size_t)N * C);
  float* pos = (float*)((char*)partials + (size_t)N * NSPLIT * sizeof(float2));

  hipMemsetAsync(d_out, 0, sizeof(float), stream);
  prep_kernel<<<N / 4, 256, 0, stream>>>(X, Y, Xf8, Yf8, pos);
  gemm_lse_kernel<<<64 * NSPLIT, 256, 0, stream>>>(Xf8, Yf8, partials);
  combine_kernel<<<N / 256, 256, 0, stream>>>(partials, pos, out);
}